// Round 6
// baseline (234.347 us; speedup 1.0000x reference)
//
#include <hip/hip_runtime.h>

// ---------------------------------------------------------------------------
// NNSensorResponse: out[s,t] = sum_{b,n} sigmoid(MLPp(x))*MLPa(x)*mask * gauss(t-z)
// B=4,N=8000 (BN=32000), F_IN=3, HID=128, S=1024, T=1024, sigma runtime (=5.0).
// Gaussian band-limited (sigma=5 -> +-31 ticks): 16 buckets of 64-tick
// granularity, each owning a 128-tick span.
// R6: hidden-state matrices written in BUCKET-SORTED order (k_prep runs after
// the counting sort, gathers x via list). k_main's A-fragment loads are now
// sequential coalesced streams (R5's random-row gather was the regression:
// 97 MB scattered fetch at 1.3 TB/s). k_main keeps the barrier-free form and
// no longer touches `list`. Gauss + W2 shuffle fused into k_prep; d_out
// zeroing fused into k_count. 5 kernels.
// ---------------------------------------------------------------------------

#define BN_E   32000
#define NBLK   125          // BN_E / 256
#define HIDW   128
#define S_DIM  1024
#define T_DIM  1024
#define NBKT   16
#define KSPL   8
#define MAXPAD (BN_E + NBKT * 31)        // max padded list length (32496)
#define MAXCG  ((MAXPAD + 31) / 32)      // max 32-electron chunks (1016)
#define INV_SQRT_2PI 0.3989422804f

typedef __attribute__((ext_vector_type(8))) unsigned short u16x8;
typedef __attribute__((ext_vector_type(8))) __bf16         bf16x8;
typedef __attribute__((ext_vector_type(4))) float          f32x4;

static __device__ __forceinline__ unsigned short f2bf(float f) {
    union { float f; unsigned int u; } v; v.f = f;
    unsigned int r = v.u + 0x7FFFu + ((v.u >> 16) & 1u);   // RNE, inputs finite
    return (unsigned short)(r >> 16);
}

static __device__ __forceinline__ f32x4 mfma16(u16x8 a, u16x8 b, f32x4 c) {
    return __builtin_amdgcn_mfma_f32_16x16x32_bf16(
        __builtin_bit_cast(bf16x8, a), __builtin_bit_cast(bf16x8, b), c, 0, 0, 0);
}

static __device__ __forceinline__ int bucket_of(float z) {
    int b = (int)floorf((z - 31.f) * (1.f / 64.f));
    return min(max(b, 0), NBKT - 1);
}

// ---------------- sort: block hist -> scan -> scatter (+ d_out zero) --------

// blocks [0,NBLK): per-block LDS histogram. blocks [NBLK, NBLK+1024): zero out.
__global__ __launch_bounds__(256) void k_count(const float* __restrict__ z,
                                               int* __restrict__ bc,
                                               float* __restrict__ out) {
    int bx = blockIdx.x;
    if (bx >= NBLK) {                 // zero d_out: 1024 blk * 256 thr * 16B = 4MB
        int idx = (bx - NBLK) * 256 + threadIdx.x;
        ((f32x4*)out)[idx] = (f32x4){0.f, 0.f, 0.f, 0.f};
        return;
    }
    __shared__ int h[NBKT];
    if (threadIdx.x < NBKT) h[threadIdx.x] = 0;
    __syncthreads();
    int e = bx * 256 + threadIdx.x;   // BN_E % 256 == 0
    atomicAdd(&h[bucket_of(z[e])], 1);
    __syncthreads();
    if (threadIdx.x < NBKT) bc[bx * NBKT + threadIdx.x] = h[threadIdx.x];
}

// meta[0..15]=cnt, meta[32..47]=PADDED start (mult 32), meta[48]=padded total.
// base[blk][b] = intra-bucket offset of block blk. Parallel 2-phase scan.
__global__ __launch_bounds__(256) void k_scan2(const int* __restrict__ bc,
                                               int* meta, int* __restrict__ base) {
    __shared__ int part[16][16];     // [seg][b]
    __shared__ int segoff[16][16];
    int t = threadIdx.x, b = t & 15, seg = t >> 4;    // 16 segs x 8 blocks
    int v[8]; int sum = 0;
#pragma unroll
    for (int i = 0; i < 8; ++i) {
        int blk = seg * 8 + i;
        v[i] = (blk < NBLK) ? bc[blk * NBKT + b] : 0;
        sum += v[i];
    }
    part[seg][b] = sum;
    __syncthreads();
    if (t < NBKT) {                  // t = bucket
        int run = 0;
        for (int s = 0; s < 16; ++s) { segoff[s][t] = run; run += part[s][t]; }
        meta[t] = run;               // cnt
    }
    __syncthreads();
    if (t == 0) {
        int s = 0;
        for (int i = 0; i < NBKT; ++i) {
            meta[32 + i] = s;
            s += ((meta[i] + 31) >> 5) << 5;          // padded bucket length
        }
        meta[48] = s;
    }
    int run = segoff[seg][b];
#pragma unroll
    for (int i = 0; i < 8; ++i) {
        int blk = seg * 8 + i;
        if (blk < NBLK) { base[blk * NBKT + b] = run; run += v[i]; }
    }
}

// deterministic scatter using LDS ranks into padded list. grid: NBLK x 256.
__global__ __launch_bounds__(256) void k_fill(const float* __restrict__ z,
                                              const int* __restrict__ meta,
                                              const int* __restrict__ base,
                                              int* __restrict__ list) {
    __shared__ int h[NBKT];
    if (threadIdx.x < NBKT) h[threadIdx.x] = 0;
    __syncthreads();
    int e = blockIdx.x * 256 + threadIdx.x;
    int b = bucket_of(z[e]);
    int r = atomicAdd(&h[b], 1);
    list[meta[32 + b] + base[blockIdx.x * NBKT + b] + r] = e;
}

// ---------------- prep: SORTED hidden states + Gaussian tiles + W2 shuffle --
// blocks [0, MAXCG): one per 32-electron sorted chunk. Computes Hp/Ha rows in
//   sorted padded order (pads -> 0) and the GT tile (coef*mask folded, pads 0).
// blocks [MAXCG, MAXCG+128): W2 -> MFMA fragment order (coalesced in s).
__global__ __launch_bounds__(256) void k_prep(
    const float* __restrict__ x, const float* __restrict__ zg,
    const float* __restrict__ maskg, const float* __restrict__ sigp,
    const float* __restrict__ Wp1, const float* __restrict__ bp1,
    const float* __restrict__ Wa1, const float* __restrict__ ba1,
    const float* __restrict__ Wp2, const float* __restrict__ Wa2,
    const int* __restrict__ meta, const int* __restrict__ list,
    unsigned short* __restrict__ HpS, unsigned short* __restrict__ HaS,
    unsigned short* __restrict__ GT,
    unsigned short* __restrict__ WfP, unsigned short* __restrict__ WfA) {
    int bx = blockIdx.x;
    if (bx < MAXCG) {
        int pos0 = bx * 32;
        if (pos0 >= meta[48]) return;
        int b = 15;
        while (meta[32 + b] > pos0) --b;      // chunk never crosses a bucket
        int tb = b * 64, cnt = meta[b], pstart = meta[32 + b];
        int tid = threadIdx.x;

        // ---- hidden states: tid = e_l(32) x part(8); j = part*16 + i ----
        {
            int e_l = tid >> 3, part = tid & 7;
            int pos = pos0 + e_l;
            bool real = (pos - pstart) < cnt;
            int ev = real ? list[pos] : 0;
            float x0 = 0.f, x1 = 0.f, x2 = 0.f;
            if (real) { x0 = x[ev * 3]; x1 = x[ev * 3 + 1]; x2 = x[ev * 3 + 2]; }
            unsigned short hp[16], ha[16];
#pragma unroll
            for (int i = 0; i < 16; ++i) {
                int j = part * 16 + i;
                float hv = x0 * Wp1[j] + x1 * Wp1[HIDW + j] + x2 * Wp1[2 * HIDW + j] + bp1[j];
                float av = x0 * Wa1[j] + x1 * Wa1[HIDW + j] + x2 * Wa1[2 * HIDW + j] + ba1[j];
                hp[i] = real ? f2bf(fmaxf(hv, 0.f)) : (unsigned short)0;
                ha[i] = real ? f2bf(fmaxf(av, 0.f)) : (unsigned short)0;
            }
            uint4* dp = (uint4*)&HpS[pos * HIDW + part * 16];
            uint4* da = (uint4*)&HaS[pos * HIDW + part * 16];
            dp[0] = ((uint4*)hp)[0]; dp[1] = ((uint4*)hp)[1];
            da[0] = ((uint4*)ha)[0]; da[1] = ((uint4*)ha)[1];
        }

        // ---- Gaussian tile: tid = tg(8) x e2(32); 16 ticks per thread ----
        {
            int e2 = tid & 31, tg = tid >> 5;
            int pos2 = pos0 + e2;
            bool real2 = (pos2 - pstart) < cnt;
            int ev2 = real2 ? list[pos2] : 0;
            float sigma = sigp[0];
            float coef = INV_SQRT_2PI / sigma;
            float nis2 = -1.f / (2.f * sigma * sigma);
            float zz = real2 ? zg[ev2] : 0.f;
            float cm = real2 ? coef * maskg[ev2] : 0.f;
            unsigned short* dst = GT + bx * 4096;
#pragma unroll
            for (int k = 0; k < 16; ++k) {
                int tl = tg * 16 + k;
                float d = (float)(tb + tl) - zz;
                dst[tl * 32 + e2] = f2bf(cm * __expf(d * d * nis2));
            }
        }
    } else {
        int bid = bx - MAXCG;                       // 0..127
        const float* src = (bid & 64) ? Wa2 : Wp2;
        unsigned short* dst = (bid & 64) ? WfA : WfP;
        int rem = bid & 63;
        int kq = rem >> 2;                          // ks*4+q
        int s  = (rem & 3) * 256 + threadIdx.x;
        int ks = kq >> 2, q = kq & 3;
        unsigned short fr[8];
#pragma unroll
        for (int j = 0; j < 8; ++j)
            fr[j] = f2bf(src[(ks * 32 + q * 8 + j) * S_DIM + s]);
        ((u16x8*)dst)[kq * S_DIM + s] = *(u16x8*)fr;
    }
}

// ---------------- main fused kernel (barrier-free, sorted streams) ----------
// grid: (8 s_tiles, 16 buckets, KSPL), 256 threads (4 waves).
__global__ __launch_bounds__(256, 2) void k_main(
    const unsigned short* __restrict__ HpS, const unsigned short* __restrict__ HaS,
    const unsigned short* __restrict__ WfP, const unsigned short* __restrict__ WfA,
    const float* __restrict__ bp2, const float* __restrict__ ba2,
    const int* __restrict__ meta, const unsigned short* __restrict__ GT,
    float* __restrict__ out) {

    const int s0     = blockIdx.x * 128;
    const int bk     = blockIdx.y;
    const int tb     = bk * 64;                // t span [tb, tb+128)
    const int cnt    = meta[bk];
    const int pstart = meta[32 + bk];          // padded, multiple of 32
    const int nch    = (cnt + 31) >> 5;
    const int per    = (nch + KSPL - 1) / KSPL;
    const int c0     = blockIdx.z * per;
    const int c1     = min(nch, c0 + per);
    if (c0 >= c1) return;

    const int tid = threadIdx.x;
    const int w = tid >> 6, l = tid & 63, q = l >> 4, c = l & 15;

    // only LDS: wave-private Rsp transpose buffer (no __syncthreads anywhere)
    __shared__ __align__(16) unsigned short RspL[128 * 40];

    // W2 fragments, pre-shuffled: 16 coalesced 16B loads per thread.
    const u16x8* WfPv = (const u16x8*)WfP;
    const u16x8* WfAv = (const u16x8*)WfA;
    u16x8 wP[2][4], wA[2][4];
#pragma unroll
    for (int n = 0; n < 2; ++n) {
        int sg = s0 + w * 32 + n * 16 + c;
#pragma unroll
        for (int ks = 0; ks < 4; ++ks) {
            wP[n][ks] = WfPv[(ks * 4 + q) * S_DIM + sg];
            wA[n][ks] = WfAv[(ks * 4 + q) * S_DIM + sg];
        }
    }
    float bp2v[2] = { bp2[s0 + w * 32 + c], bp2[s0 + w * 32 + 16 + c] };
    float ba2v[2] = { ba2[s0 + w * 32 + c], ba2[s0 + w * 32 + 16 + c] };

    const f32x4 z4 = { 0.f, 0.f, 0.f, 0.f };
    f32x4 acc2[2][8];
#pragma unroll
    for (int m = 0; m < 2; ++m)
#pragma unroll
        for (int n8 = 0; n8 < 8; ++n8) acc2[m][n8] = z4;

    for (int ci = c0; ci < c1; ++ci) {
        // sorted row base for this chunk: sequential, fully coalesced streams
        const unsigned short* hpr0 = HpS + (size_t)(pstart + ci * 32 + c) * HIDW;
        const unsigned short* hpr1 = hpr0 + 16 * HIDW;
        const unsigned short* har0 = HaS + (size_t)(pstart + ci * 32 + c) * HIDW;
        const unsigned short* har1 = har0 + 16 * HIDW;

        // GT B-fragments (sequential global, L2-resident)
        const unsigned short* gt = GT + (size_t)((pstart >> 5) + ci) * 4096;
        u16x8 bfr[8];
#pragma unroll
        for (int n8 = 0; n8 < 8; ++n8)
            bfr[n8] = *(const u16x8*)&gt[(n8 * 16 + c) * 32 + q * 8];

        // GEMM1: C1[e][s] = H[e][k] @ W2[k][s]; A-frags direct from global
        f32x4 aP[2][2], aA[2][2];
#pragma unroll
        for (int m = 0; m < 2; ++m)
#pragma unroll
            for (int n = 0; n < 2; ++n) { aP[m][n] = z4; aA[m][n] = z4; }
#pragma unroll
        for (int ks = 0; ks < 4; ++ks) {
            u16x8 hp0 = *(const u16x8*)&hpr0[ks * 32 + q * 8];
            u16x8 hp1 = *(const u16x8*)&hpr1[ks * 32 + q * 8];
            u16x8 ha0 = *(const u16x8*)&har0[ks * 32 + q * 8];
            u16x8 ha1 = *(const u16x8*)&har1[ks * 32 + q * 8];
#pragma unroll
            for (int n = 0; n < 2; ++n) {
                aP[0][n] = mfma16(hp0, wP[n][ks], aP[0][n]);
                aP[1][n] = mfma16(hp1, wP[n][ks], aP[1][n]);
                aA[0][n] = mfma16(ha0, wA[n][ks], aA[0][n]);
                aA[1][n] = mfma16(ha1, wA[n][ks], aA[1][n]);
            }
        }

        // epilogue1: rsp = sigmoid(p+bp2)*(a+ba2); C-layout -> RspL[s][e]
        // rows wave-private; DS ops in-order per wave -> no barrier needed
#pragma unroll
        for (int m = 0; m < 2; ++m)
#pragma unroll
            for (int n = 0; n < 2; ++n) {
                f32x4 p = aP[m][n], a = aA[m][n];
                unsigned long long pk = 0;
#pragma unroll
                for (int r = 0; r < 4; ++r) {
                    float pr = p[r] + bp2v[n];
                    float ar = a[r] + ba2v[n];
                    float sg = __builtin_amdgcn_rcpf(1.f + __expf(-pr));
                    pk |= (unsigned long long)f2bf(sg * ar) << (16 * r);
                }
                int sl = w * 32 + n * 16 + c;        // col of C1 = s
                int e0 = m * 16 + q * 4;             // row of C1 = e
                *(unsigned long long*)&RspL[sl * 40 + e0] = pk;
            }

        // GEMM2: out[s][t] += Rsp[s][e] @ G[e][t]
#pragma unroll
        for (int m = 0; m < 2; ++m) {
            u16x8 afr = *(const u16x8*)&RspL[(w * 32 + m * 16 + c) * 40 + q * 8];
#pragma unroll
            for (int n8 = 0; n8 < 8; ++n8)
                acc2[m][n8] = mfma16(afr, bfr[n8], acc2[m][n8]);
        }
    }

    // epilogue2: atomic accumulate (bucket spans overlap + ksplit)
#pragma unroll
    for (int m = 0; m < 2; ++m)
#pragma unroll
        for (int n8 = 0; n8 < 8; ++n8) {
            int t = tb + n8 * 16 + c;
            if (t < T_DIM) {
                int srow = s0 + w * 32 + m * 16 + q * 4;
#pragma unroll
                for (int r = 0; r < 4; ++r)
                    atomicAdd(&out[(srow + r) * T_DIM + t], acc2[m][n8][r]);
            }
        }
}

// ---------------- launch ----------------

extern "C" void kernel_launch(void* const* d_in, const int* in_sizes, int n_in,
                              void* d_out, int out_size, void* d_ws, size_t ws_size,
                              hipStream_t stream) {
    const float* x    = (const float*)d_in[0];
    const float* zp   = (const float*)d_in[1];
    const float* mask = (const float*)d_in[2];
    const float* Wp1  = (const float*)d_in[3];
    const float* bp1  = (const float*)d_in[4];
    const float* Wp2  = (const float*)d_in[5];
    const float* bp2  = (const float*)d_in[6];
    const float* Wa1  = (const float*)d_in[7];
    const float* ba1  = (const float*)d_in[8];
    const float* Wa2  = (const float*)d_in[9];
    const float* ba2  = (const float*)d_in[10];
    const float* sig  = (const float*)d_in[11];

    char* ws = (char*)d_ws;
    unsigned short* HpS  = (unsigned short*)(ws);                      // 8,318,976 B (MAXPAD*256)
    unsigned short* HaS  = (unsigned short*)(ws + 8320000);            // 8,318,976 B
    unsigned short* WfP  = (unsigned short*)(ws + 16640000);           //   262,144 B
    unsigned short* WfA  = (unsigned short*)(ws + 16902144);           //   262,144 B
    int*            meta = (int*)(ws + 17164288);                      //       256 B
    int*            list = (int*)(ws + 17164544);                      //   130,048 B
    int*            bc   = (int*)(ws + 17294592);                      //     8,000 B
    int*            base = (int*)(ws + 17302592);                      //     8,000 B
    unsigned short* GT   = (unsigned short*)(ws + 17310592);           // 8,323,072 B
    // total ws ~25.6 MB

    k_count<<<NBLK + 1024, 256, 0, stream>>>(zp, bc, (float*)d_out);
    k_scan2<<<1, 256, 0, stream>>>(bc, meta, base);
    k_fill<<<NBLK, 256, 0, stream>>>(zp, meta, base, list);
    k_prep<<<MAXCG + 128, 256, 0, stream>>>(x, zp, mask, sig,
                                            Wp1, bp1, Wa1, ba1, Wp2, Wa2,
                                            meta, list, HpS, HaS, GT, WfP, WfA);
    k_main<<<dim3(8, NBKT, KSPL), 256, 0, stream>>>(
        HpS, HaS, WfP, WfA, bp2, ba2, meta, GT, (float*)d_out);
}

// Round 7
// 175.625 us; speedup vs baseline: 1.3344x; 1.3344x over previous
//
#include <hip/hip_runtime.h>

// ---------------------------------------------------------------------------
// NNSensorResponse: out[s,t] = sum_{b,n} sigmoid(MLPp(x))*MLPa(x)*mask * gauss(t-z)
// B=4,N=8000 (BN=32000), F_IN=3, HID=128, S=1024, T=1024, sigma runtime (=5.0).
// Gaussian band-limited (sigma=5 -> +-31 ticks): 16 buckets of 64-tick
// granularity, each owning a 128-tick span.
// R7: (1) Hp/Ha/GT stored in MFMA-FRAGMENT order (k_prep) -> k_main staging is
//     a linear 24KB memcpy into LDS, ds_read_b128 2-way banks (free), no pad.
// (2) LDS staging back (R6's direct-global was 4x L1-amplified: 97MB fetch).
// (3) XCD swizzle: the 8 s_tile blocks sharing a chunk stream sit on one XCD
//     (grid.x=bk*KSPL+kspl, grid.y=s_tile; round-robin dispatch keeps y-varying
//     blocks on the same XCD) -> A-stream fetched once per XCD, L2-shared.
// (4) KSPL=4: halves output atomics vs R6.
// ---------------------------------------------------------------------------

#define BN_E   32000
#define NBLK   125          // BN_E / 256
#define HIDW   128
#define S_DIM  1024
#define T_DIM  1024
#define NBKT   16
#define KSPL   4
#define MAXPAD (BN_E + NBKT * 31)        // max padded list length (32496)
#define MAXCG  ((MAXPAD + 31) / 32)      // max 32-electron chunks (1016)
#define INV_SQRT_2PI 0.3989422804f

typedef __attribute__((ext_vector_type(8))) unsigned short u16x8;
typedef __attribute__((ext_vector_type(8))) __bf16         bf16x8;
typedef __attribute__((ext_vector_type(4))) float          f32x4;

static __device__ __forceinline__ unsigned short f2bf(float f) {
    union { float f; unsigned int u; } v; v.f = f;
    unsigned int r = v.u + 0x7FFFu + ((v.u >> 16) & 1u);   // RNE, inputs finite
    return (unsigned short)(r >> 16);
}

static __device__ __forceinline__ f32x4 mfma16(u16x8 a, u16x8 b, f32x4 c) {
    return __builtin_amdgcn_mfma_f32_16x16x32_bf16(
        __builtin_bit_cast(bf16x8, a), __builtin_bit_cast(bf16x8, b), c, 0, 0, 0);
}

static __device__ __forceinline__ int bucket_of(float z) {
    int b = (int)floorf((z - 31.f) * (1.f / 64.f));
    return min(max(b, 0), NBKT - 1);
}

// ---------------- sort: block hist -> scan -> scatter (+ d_out zero) --------

// blocks [0,NBLK): per-block LDS histogram. blocks [NBLK, NBLK+1024): zero out.
__global__ __launch_bounds__(256) void k_count(const float* __restrict__ z,
                                               int* __restrict__ bc,
                                               float* __restrict__ out) {
    int bx = blockIdx.x;
    if (bx >= NBLK) {                 // zero d_out: 1024 blk * 256 thr * 16B = 4MB
        int idx = (bx - NBLK) * 256 + threadIdx.x;
        ((f32x4*)out)[idx] = (f32x4){0.f, 0.f, 0.f, 0.f};
        return;
    }
    __shared__ int h[NBKT];
    if (threadIdx.x < NBKT) h[threadIdx.x] = 0;
    __syncthreads();
    int e = bx * 256 + threadIdx.x;   // BN_E % 256 == 0
    atomicAdd(&h[bucket_of(z[e])], 1);
    __syncthreads();
    if (threadIdx.x < NBKT) bc[bx * NBKT + threadIdx.x] = h[threadIdx.x];
}

// meta[0..15]=cnt, meta[32..47]=PADDED start (mult 32), meta[48]=padded total.
__global__ __launch_bounds__(256) void k_scan2(const int* __restrict__ bc,
                                               int* meta, int* __restrict__ base) {
    __shared__ int part[16][16];     // [seg][b]
    __shared__ int segoff[16][16];
    int t = threadIdx.x, b = t & 15, seg = t >> 4;    // 16 segs x 8 blocks
    int v[8]; int sum = 0;
#pragma unroll
    for (int i = 0; i < 8; ++i) {
        int blk = seg * 8 + i;
        v[i] = (blk < NBLK) ? bc[blk * NBKT + b] : 0;
        sum += v[i];
    }
    part[seg][b] = sum;
    __syncthreads();
    if (t < NBKT) {                  // t = bucket
        int run = 0;
        for (int s = 0; s < 16; ++s) { segoff[s][t] = run; run += part[s][t]; }
        meta[t] = run;               // cnt
    }
    __syncthreads();
    if (t == 0) {
        int s = 0;
        for (int i = 0; i < NBKT; ++i) {
            meta[32 + i] = s;
            s += ((meta[i] + 31) >> 5) << 5;          // padded bucket length
        }
        meta[48] = s;
    }
    int run = segoff[seg][b];
#pragma unroll
    for (int i = 0; i < 8; ++i) {
        int blk = seg * 8 + i;
        if (blk < NBLK) { base[blk * NBKT + b] = run; run += v[i]; }
    }
}

// deterministic scatter using LDS ranks into padded list. grid: NBLK x 256.
__global__ __launch_bounds__(256) void k_fill(const float* __restrict__ z,
                                              const int* __restrict__ meta,
                                              const int* __restrict__ base,
                                              int* __restrict__ list) {
    __shared__ int h[NBKT];
    if (threadIdx.x < NBKT) h[threadIdx.x] = 0;
    __syncthreads();
    int e = blockIdx.x * 256 + threadIdx.x;
    int b = bucket_of(z[e]);
    int r = atomicAdd(&h[b], 1);
    list[meta[32 + b] + base[blockIdx.x * NBKT + b] + r] = e;
}

// ---------------- prep: fragment-ordered Hp/Ha/GT + W2 shuffle --------------
// blocks [0, MAXCG): one per 32-electron sorted chunk.
//   Hp/Ha chunk layout (4096 shorts): unit u=(ks*4+q)*32+e_l holds
//     H[e_l][k=ks*32+q*8 .. +7] (8 shorts = 16B).
//   GT chunk layout (4096 shorts): unit u=(n8*4+q)*16+c holds
//     G[t=n8*16+c][e=q*8 .. +7], coef*mask folded, pads zero.
// blocks [MAXCG, MAXCG+128): W2 -> MFMA fragment order (coalesced in s).
__global__ __launch_bounds__(256) void k_prep(
    const float* __restrict__ x, const float* __restrict__ zg,
    const float* __restrict__ maskg, const float* __restrict__ sigp,
    const float* __restrict__ Wp1, const float* __restrict__ bp1,
    const float* __restrict__ Wa1, const float* __restrict__ ba1,
    const float* __restrict__ Wp2, const float* __restrict__ Wa2,
    const int* __restrict__ meta, const int* __restrict__ list,
    unsigned short* __restrict__ HpS, unsigned short* __restrict__ HaS,
    unsigned short* __restrict__ GT,
    unsigned short* __restrict__ WfP, unsigned short* __restrict__ WfA) {
    int bx = blockIdx.x;
    if (bx < MAXCG) {
        int pos0 = bx * 32;
        if (pos0 >= meta[48]) return;
        int b = 15;
        while (meta[32 + b] > pos0) --b;      // chunk never crosses a bucket
        int tb = b * 64, cnt = meta[b], pstart = meta[32 + b];
        int tid = threadIdx.x;

        __shared__ float zzL[32], cmL[32];
        if (tid < 32) {
            int pos = pos0 + tid;
            bool real = (pos - pstart) < cnt;
            int ev = real ? list[pos] : 0;
            float sigma = sigp[0];
            zzL[tid] = real ? zg[ev] : 0.f;
            cmL[tid] = real ? (INV_SQRT_2PI / sigma) * maskg[ev] : 0.f;
        }
        __syncthreads();

        // ---- hidden states (fragment order) ----
        {
            int e_l = tid >> 3, part = tid & 7;       // j = part*16 + i
            int pos = pos0 + e_l;
            bool real = (pos - pstart) < cnt;
            int ev = real ? list[pos] : 0;
            float x0 = 0.f, x1 = 0.f, x2 = 0.f;
            if (real) { x0 = x[ev * 3]; x1 = x[ev * 3 + 1]; x2 = x[ev * 3 + 2]; }
            unsigned short hp[16], ha[16];
#pragma unroll
            for (int i = 0; i < 16; ++i) {
                int j = part * 16 + i;
                float hv = x0 * Wp1[j] + x1 * Wp1[HIDW + j] + x2 * Wp1[2 * HIDW + j] + bp1[j];
                float av = x0 * Wa1[j] + x1 * Wa1[HIDW + j] + x2 * Wa1[2 * HIDW + j] + ba1[j];
                hp[i] = real ? f2bf(fmaxf(hv, 0.f)) : (unsigned short)0;
                ha[i] = real ? f2bf(fmaxf(av, 0.f)) : (unsigned short)0;
            }
            // two 16B units: k0 = part*16 (+8 for the second)
#pragma unroll
            for (int h2 = 0; h2 < 2; ++h2) {
                int k0 = part * 16 + h2 * 8;
                int u = ((k0 >> 5) * 4 + ((k0 >> 3) & 3)) * 32 + e_l;
                *(uint4*)&HpS[(size_t)bx * 4096 + u * 8] = ((uint4*)hp)[h2];
                *(uint4*)&HaS[(size_t)bx * 4096 + u * 8] = ((uint4*)ha)[h2];
            }
        }

        // ---- Gaussian tile (fragment order): 2 units x 8 electrons ----
        {
            float sigma = sigp[0];
            float nis2 = -1.f / (2.f * sigma * sigma);
#pragma unroll
            for (int uu = 0; uu < 2; ++uu) {
                int u = tid * 2 + uu;                 // 0..511
                int n8 = u >> 6, q = (u >> 4) & 3, c = u & 15;
                float tt = (float)(tb + n8 * 16 + c);
                unsigned short g8[8];
#pragma unroll
                for (int j = 0; j < 8; ++j) {
                    int e = q * 8 + j;
                    float d = tt - zzL[e];
                    g8[j] = f2bf(cmL[e] * __expf(d * d * nis2));
                }
                *(uint4*)&GT[(size_t)bx * 4096 + u * 8] = *(uint4*)g8;
            }
        }
    } else {
        int bid = bx - MAXCG;                       // 0..127
        const float* src = (bid & 64) ? Wa2 : Wp2;
        unsigned short* dst = (bid & 64) ? WfA : WfP;
        int rem = bid & 63;
        int kq = rem >> 2;                          // ks*4+q
        int s  = (rem & 3) * 256 + threadIdx.x;
        int ks = kq >> 2, q = kq & 3;
        unsigned short fr[8];
#pragma unroll
        for (int j = 0; j < 8; ++j)
            fr[j] = f2bf(src[(ks * 32 + q * 8 + j) * S_DIM + s]);
        ((u16x8*)dst)[kq * S_DIM + s] = *(u16x8*)fr;
    }
}

// ---------------- main fused kernel (LDS-staged, XCD-swizzled) --------------
// grid: (NBKT*KSPL, 8 s_tiles), 256 threads (4 waves).
__global__ __launch_bounds__(256, 2) void k_main(
    const unsigned short* __restrict__ HpS, const unsigned short* __restrict__ HaS,
    const unsigned short* __restrict__ WfP, const unsigned short* __restrict__ WfA,
    const float* __restrict__ bp2, const float* __restrict__ ba2,
    const int* __restrict__ meta, const unsigned short* __restrict__ GT,
    float* __restrict__ out) {

    const int bk     = blockIdx.x / KSPL;
    const int kspl   = blockIdx.x % KSPL;
    const int s0     = blockIdx.y * 128;
    const int tb     = bk * 64;                // t span [tb, tb+128)
    const int cnt    = meta[bk];
    const int pstart = meta[32 + bk];          // padded, multiple of 32
    const int nch    = (cnt + 31) >> 5;
    const int per    = (nch + KSPL - 1) / KSPL;
    const int c0     = kspl * per;
    const int c1     = min(nch, c0 + per);
    if (c0 >= c1) return;                      // uniform across block

    const int tid = threadIdx.x;
    const int w = tid >> 6, l = tid & 63, q = l >> 4, c = l & 15;

    // LDS: staged chunk (Hp 512 | Ha 512 | GT 512 uint4 = 24 KB) + Rsp 10 KB
    __shared__ __align__(16) uint4 StageL[1536];
    __shared__ __align__(16) unsigned short RspL[128 * 40];

    // W2 fragments, pre-shuffled: 16 coalesced 16B loads per thread.
    const u16x8* WfPv = (const u16x8*)WfP;
    const u16x8* WfAv = (const u16x8*)WfA;
    u16x8 wP[2][4], wA[2][4];
#pragma unroll
    for (int n = 0; n < 2; ++n) {
        int sg = s0 + w * 32 + n * 16 + c;
#pragma unroll
        for (int ks = 0; ks < 4; ++ks) {
            wP[n][ks] = WfPv[(ks * 4 + q) * S_DIM + sg];
            wA[n][ks] = WfAv[(ks * 4 + q) * S_DIM + sg];
        }
    }
    float bp2v[2] = { bp2[s0 + w * 32 + c], bp2[s0 + w * 32 + 16 + c] };
    float ba2v[2] = { ba2[s0 + w * 32 + c], ba2[s0 + w * 32 + 16 + c] };

    const f32x4 z4 = { 0.f, 0.f, 0.f, 0.f };
    f32x4 acc2[2][8];
#pragma unroll
    for (int m = 0; m < 2; ++m)
#pragma unroll
        for (int n8 = 0; n8 < 8; ++n8) acc2[m][n8] = z4;

    const uint4* Hp4 = (const uint4*)HpS;
    const uint4* Ha4 = (const uint4*)HaS;
    const uint4* Gt4 = (const uint4*)GT;
    const int cgBase = pstart >> 5;            // first chunk index of bucket

    const u16x8* St = (const u16x8*)StageL;

    for (int ci = c0; ci < c1; ++ci) {
        const size_t cb = (size_t)(cgBase + ci) * 512;
        __syncthreads();                       // prior chunk's reads done
        // linear stage: 6 x 16B per thread, coalesced
        StageL[tid]        = Hp4[cb + tid];
        StageL[256 + tid]  = Hp4[cb + 256 + tid];
        StageL[512 + tid]  = Ha4[cb + tid];
        StageL[768 + tid]  = Ha4[cb + 256 + tid];
        StageL[1024 + tid] = Gt4[cb + tid];
        StageL[1280 + tid] = Gt4[cb + 256 + tid];
        __syncthreads();

        // GEMM1: C1[e][s] = H[e][k] @ W2[k][s]  (M=e 32, N=s 32/wave, K=128)
        f32x4 aP[2][2], aA[2][2];
#pragma unroll
        for (int m = 0; m < 2; ++m)
#pragma unroll
            for (int n = 0; n < 2; ++n) { aP[m][n] = z4; aA[m][n] = z4; }
#pragma unroll
        for (int ks = 0; ks < 4; ++ks) {
            u16x8 hp0 = St[(ks * 4 + q) * 32 + c];
            u16x8 hp1 = St[(ks * 4 + q) * 32 + c + 16];
            u16x8 ha0 = St[512 + (ks * 4 + q) * 32 + c];
            u16x8 ha1 = St[512 + (ks * 4 + q) * 32 + c + 16];
#pragma unroll
            for (int n = 0; n < 2; ++n) {
                aP[0][n] = mfma16(hp0, wP[n][ks], aP[0][n]);
                aP[1][n] = mfma16(hp1, wP[n][ks], aP[1][n]);
                aA[0][n] = mfma16(ha0, wA[n][ks], aA[0][n]);
                aA[1][n] = mfma16(ha1, wA[n][ks], aA[1][n]);
            }
        }

        // epilogue1: rsp = sigmoid(p+bp2)*(a+ba2); C-layout -> RspL[s][e]
        // rows wave-private; DS ops in-order per wave -> no barrier needed
#pragma unroll
        for (int m = 0; m < 2; ++m)
#pragma unroll
            for (int n = 0; n < 2; ++n) {
                f32x4 p = aP[m][n], a = aA[m][n];
                unsigned long long pk = 0;
#pragma unroll
                for (int r = 0; r < 4; ++r) {
                    float pr = p[r] + bp2v[n];
                    float ar = a[r] + ba2v[n];
                    float sg = __builtin_amdgcn_rcpf(1.f + __expf(-pr));
                    pk |= (unsigned long long)f2bf(sg * ar) << (16 * r);
                }
                int sl = w * 32 + n * 16 + c;        // col of C1 = s
                int e0 = m * 16 + q * 4;             // row of C1 = e
                *(unsigned long long*)&RspL[sl * 40 + e0] = pk;
            }

        // GEMM2: out[s][t] += Rsp[s][e] @ G[e][t]  (B-frags from staged GT)
        u16x8 bfr[8];
#pragma unroll
        for (int n8 = 0; n8 < 8; ++n8)
            bfr[n8] = St[1024 + (n8 * 4 + q) * 16 + c];
#pragma unroll
        for (int m = 0; m < 2; ++m) {
            u16x8 afr = *(const u16x8*)&RspL[(w * 32 + m * 16 + c) * 40 + q * 8];
#pragma unroll
            for (int n8 = 0; n8 < 8; ++n8)
                acc2[m][n8] = mfma16(afr, bfr[n8], acc2[m][n8]);
        }
    }

    // epilogue2: atomic accumulate (bucket spans overlap + ksplit)
#pragma unroll
    for (int m = 0; m < 2; ++m)
#pragma unroll
        for (int n8 = 0; n8 < 8; ++n8) {
            int t = tb + n8 * 16 + c;
            if (t < T_DIM) {
                int srow = s0 + w * 32 + m * 16 + q * 4;
#pragma unroll
                for (int r = 0; r < 4; ++r)
                    atomicAdd(&out[(srow + r) * T_DIM + t], acc2[m][n8][r]);
            }
        }
}

// ---------------- launch ----------------

extern "C" void kernel_launch(void* const* d_in, const int* in_sizes, int n_in,
                              void* d_out, int out_size, void* d_ws, size_t ws_size,
                              hipStream_t stream) {
    const float* x    = (const float*)d_in[0];
    const float* zp   = (const float*)d_in[1];
    const float* mask = (const float*)d_in[2];
    const float* Wp1  = (const float*)d_in[3];
    const float* bp1  = (const float*)d_in[4];
    const float* Wp2  = (const float*)d_in[5];
    const float* bp2  = (const float*)d_in[6];
    const float* Wa1  = (const float*)d_in[7];
    const float* ba1  = (const float*)d_in[8];
    const float* Wa2  = (const float*)d_in[9];
    const float* ba2  = (const float*)d_in[10];
    const float* sig  = (const float*)d_in[11];

    char* ws = (char*)d_ws;
    unsigned short* HpS  = (unsigned short*)(ws);                      // 8,323,072 B
    unsigned short* HaS  = (unsigned short*)(ws + 8323072);            // 8,323,072 B
    unsigned short* WfP  = (unsigned short*)(ws + 16646144);           //   262,144 B
    unsigned short* WfA  = (unsigned short*)(ws + 16908288);           //   262,144 B
    int*            meta = (int*)(ws + 17170432);                      //       256 B
    int*            list = (int*)(ws + 17170688);                      //   130,048 B
    int*            bc   = (int*)(ws + 17300736);                      //     8,000 B
    int*            base = (int*)(ws + 17308736);                      //     8,000 B
    unsigned short* GT   = (unsigned short*)(ws + 17316736);           // 8,323,072 B
    // total ws ~25.6 MB

    k_count<<<NBLK + 1024, 256, 0, stream>>>(zp, bc, (float*)d_out);
    k_scan2<<<1, 256, 0, stream>>>(bc, meta, base);
    k_fill<<<NBLK, 256, 0, stream>>>(zp, meta, base, list);
    k_prep<<<MAXCG + 128, 256, 0, stream>>>(x, zp, mask, sig,
                                            Wp1, bp1, Wa1, ba1, Wp2, Wa2,
                                            meta, list, HpS, HaS, GT, WfP, WfA);
    k_main<<<dim3(NBKT * KSPL, 8, 1), 256, 0, stream>>>(
        HpS, HaS, WfP, WfA, bp2, ba2, meta, GT, (float*)d_out);
}

// Round 8
// 153.337 us; speedup vs baseline: 1.5283x; 1.1454x over previous
//
#include <hip/hip_runtime.h>

// ---------------------------------------------------------------------------
// NNSensorResponse: out[s,t] = sum_{b,n} sigmoid(MLPp(x))*MLPa(x)*mask * gauss(t-z)
// B=4,N=8000 (BN=32000), F_IN=3, HID=128, S=1024, T=1024, sigma runtime (=5.0).
// Gaussian band-limited (sigma=5 -> +-31 ticks): 16 buckets of 64-tick
// granularity, each owning a 128-tick span. Hp/Ha/GT stored in MFMA-fragment
// order, bucket-sorted (k_prep); k_main stages Hp/Ha chunks to LDS.
// R8: (1) 64-wide s_tiles (16) + KSPL=4 -> 1024 blocks = 4/CU (same atomic
//     total as R7); regs halve -> 4 waves/SIMD under launch_bounds(256,4).
// (2) register prefetch of next chunk's Hp/Ha (overlap L2 latency w/ compute).
// (3) GT B-frags direct from global (coalesced 1KB/wave, L1-shared) - LDS
//     stage 24->16KB, -32KB LDS reads per chunk.
// (4) W1 in LDS in k_prep; scan fused into k_fill (one fewer node).
// ---------------------------------------------------------------------------

#define BN_E   32000
#define NBLK   125          // BN_E / 256
#define HIDW   128
#define S_DIM  1024
#define T_DIM  1024
#define NBKT   16
#define KSPL   4
#define MAXPAD (BN_E + NBKT * 31)        // max padded list length (32496)
#define MAXCG  ((MAXPAD + 31) / 32)      // max 32-electron chunks (1016)
#define INV_SQRT_2PI 0.3989422804f

typedef __attribute__((ext_vector_type(8))) unsigned short u16x8;
typedef __attribute__((ext_vector_type(8))) __bf16         bf16x8;
typedef __attribute__((ext_vector_type(4))) float          f32x4;

static __device__ __forceinline__ unsigned short f2bf(float f) {
    union { float f; unsigned int u; } v; v.f = f;
    unsigned int r = v.u + 0x7FFFu + ((v.u >> 16) & 1u);   // RNE, inputs finite
    return (unsigned short)(r >> 16);
}

static __device__ __forceinline__ f32x4 mfma16(u16x8 a, u16x8 b, f32x4 c) {
    return __builtin_amdgcn_mfma_f32_16x16x32_bf16(
        __builtin_bit_cast(bf16x8, a), __builtin_bit_cast(bf16x8, b), c, 0, 0, 0);
}

static __device__ __forceinline__ int bucket_of(float z) {
    int b = (int)floorf((z - 31.f) * (1.f / 64.f));
    return min(max(b, 0), NBKT - 1);
}

// ---------------- sort stage 1: block hist (+ d_out zero) -------------------
// blocks [0,NBLK): per-block LDS histogram. blocks [NBLK, NBLK+1024): zero out.
__global__ __launch_bounds__(256) void k_count(const float* __restrict__ z,
                                               int* __restrict__ bc,
                                               float* __restrict__ out) {
    int bx = blockIdx.x;
    if (bx >= NBLK) {                 // zero d_out: 1024 blk * 256 thr * 16B = 4MB
        int idx = (bx - NBLK) * 256 + threadIdx.x;
        ((f32x4*)out)[idx] = (f32x4){0.f, 0.f, 0.f, 0.f};
        return;
    }
    __shared__ int h[NBKT];
    if (threadIdx.x < NBKT) h[threadIdx.x] = 0;
    __syncthreads();
    int e = bx * 256 + threadIdx.x;   // BN_E % 256 == 0
    atomicAdd(&h[bucket_of(z[e])], 1);
    __syncthreads();
    if (threadIdx.x < NBKT) bc[bx * NBKT + threadIdx.x] = h[threadIdx.x];
}

// ---------------- sort stage 2: fused scan+scatter. grid: NBLK x 256 --------
// Each block redoes the (cheap) scan from bc locally, computes its own base,
// scatters its 256 electrons. Block 0 additionally publishes meta:
// meta[0..15]=cnt, meta[32..47]=PADDED start (mult 32), meta[48]=padded total.
__global__ __launch_bounds__(256) void k_fillscan(const float* __restrict__ z,
                                                  const int* __restrict__ bc,
                                                  int* __restrict__ meta,
                                                  int* __restrict__ list) {
    __shared__ int part[16][16];     // [seg][b]
    __shared__ int segoff[16][16];
    __shared__ int cntL[NBKT], pstartL[NBKT], baseL[NBKT], h[NBKT];
    int t = threadIdx.x, b = t & 15, seg = t >> 4;    // 16 segs x 8 blocks
    int v[8]; int sum = 0;
#pragma unroll
    for (int i = 0; i < 8; ++i) {
        int blk = seg * 8 + i;
        v[i] = (blk < NBLK) ? bc[blk * NBKT + b] : 0;
        sum += v[i];
    }
    part[seg][b] = sum;
    if (t < NBKT) h[t] = 0;
    __syncthreads();
    if (t < NBKT) {                  // t = bucket
        int run = 0;
        for (int s = 0; s < 16; ++s) { segoff[s][t] = run; run += part[s][t]; }
        cntL[t] = run;
    }
    __syncthreads();
    if (t == 0) {
        int s = 0;
        for (int i = 0; i < NBKT; ++i) {
            pstartL[i] = s;
            s += ((cntL[i] + 31) >> 5) << 5;          // padded bucket length
        }
        if (blockIdx.x == 0) {
            for (int i = 0; i < NBKT; ++i) { meta[i] = cntL[i]; meta[32 + i] = pstartL[i]; }
            meta[48] = s;
        }
    }
    __syncthreads();
    if (t < NBKT) {                  // own base for this block
        int me = blockIdx.x;
        int run = segoff[me >> 3][t];
        for (int k = 0; k < (me & 7); ++k)
            run += bc[((me >> 3) * 8 + k) * NBKT + t];
        baseL[t] = pstartL[t] + run;
    }
    __syncthreads();
    int e = blockIdx.x * 256 + t;
    int b2 = bucket_of(z[e]);
    int r = atomicAdd(&h[b2], 1);
    list[baseL[b2] + r] = e;
}

// ---------------- prep: fragment-ordered Hp/Ha/GT + W2 shuffle --------------
// blocks [0, MAXCG): one per 32-electron sorted chunk.
//   Hp/Ha chunk (4096 shorts): unit u=(ks*4+q)*32+e_l holds H[e_l][k=ks*32+q*8..+7].
//   GT chunk (4096 shorts): unit u=(n8*4+q)*16+c holds G[t=n8*16+c][e=q*8..+7].
// blocks [MAXCG, MAXCG+128): W2 -> MFMA fragment order (coalesced in s).
__global__ __launch_bounds__(256) void k_prep(
    const float* __restrict__ x, const float* __restrict__ zg,
    const float* __restrict__ maskg, const float* __restrict__ sigp,
    const float* __restrict__ Wp1, const float* __restrict__ bp1,
    const float* __restrict__ Wa1, const float* __restrict__ ba1,
    const float* __restrict__ Wp2, const float* __restrict__ Wa2,
    const int* __restrict__ meta, const int* __restrict__ list,
    unsigned short* __restrict__ HpS, unsigned short* __restrict__ HaS,
    unsigned short* __restrict__ GT,
    unsigned short* __restrict__ WfP, unsigned short* __restrict__ WfA) {
    int bx = blockIdx.x;
    if (bx < MAXCG) {
        int pos0 = bx * 32;
        if (pos0 >= meta[48]) return;
        int b = 15;
        while (meta[32 + b] > pos0) --b;      // chunk never crosses a bucket
        int tb = b * 64, cnt = meta[b], pstart = meta[32 + b];
        int tid = threadIdx.x;

        // W1/biases into LDS: [Wp1 384][bp1 128][Wa1 384][ba1 128] floats
        __shared__ float W1L[1024];
        __shared__ float zzL[32], cmL[32];
        if (tid < 96)                        ((float4*)W1L)[tid]              = ((const float4*)Wp1)[tid];
        else if (tid < 128)                  ((float4*)(W1L + 384))[tid - 96] = ((const float4*)bp1)[tid - 96];
        else if (tid < 224)                  ((float4*)(W1L + 512))[tid - 128]= ((const float4*)Wa1)[tid - 128];
        else                                 ((float4*)(W1L + 896))[tid - 224]= ((const float4*)ba1)[tid - 224];
        if (tid < 32) {
            int pos = pos0 + tid;
            bool real = (pos - pstart) < cnt;
            int ev = real ? list[pos] : 0;
            float sigma = sigp[0];
            zzL[tid] = real ? zg[ev] : 0.f;
            cmL[tid] = real ? (INV_SQRT_2PI / sigma) * maskg[ev] : 0.f;
        }
        __syncthreads();

        // ---- hidden states (fragment order) ----
        {
            int e_l = tid >> 3, part = tid & 7;       // j = part*16 + i
            int pos = pos0 + e_l;
            bool real = (pos - pstart) < cnt;
            int ev = real ? list[pos] : 0;
            float x0 = 0.f, x1 = 0.f, x2 = 0.f;
            if (real) { x0 = x[ev * 3]; x1 = x[ev * 3 + 1]; x2 = x[ev * 3 + 2]; }
            unsigned short hp[16], ha[16];
#pragma unroll
            for (int i = 0; i < 16; ++i) {
                int j = part * 16 + i;
                float hv = x0 * W1L[j] + x1 * W1L[128 + j] + x2 * W1L[256 + j] + W1L[384 + j];
                float av = x0 * W1L[512 + j] + x1 * W1L[640 + j] + x2 * W1L[768 + j] + W1L[896 + j];
                hp[i] = real ? f2bf(fmaxf(hv, 0.f)) : (unsigned short)0;
                ha[i] = real ? f2bf(fmaxf(av, 0.f)) : (unsigned short)0;
            }
#pragma unroll
            for (int h2 = 0; h2 < 2; ++h2) {
                int k0 = part * 16 + h2 * 8;
                int u = ((k0 >> 5) * 4 + ((k0 >> 3) & 3)) * 32 + e_l;
                *(uint4*)&HpS[(size_t)bx * 4096 + u * 8] = ((uint4*)hp)[h2];
                *(uint4*)&HaS[(size_t)bx * 4096 + u * 8] = ((uint4*)ha)[h2];
            }
        }

        // ---- Gaussian tile (fragment order): 2 units x 8 electrons ----
        {
            float sigma = sigp[0];
            float nis2 = -1.f / (2.f * sigma * sigma);
#pragma unroll
            for (int uu = 0; uu < 2; ++uu) {
                int u = tid * 2 + uu;                 // 0..511
                int n8 = u >> 6, q = (u >> 4) & 3, c = u & 15;
                float tt = (float)(tb + n8 * 16 + c);
                unsigned short g8[8];
#pragma unroll
                for (int j = 0; j < 8; ++j) {
                    int e = q * 8 + j;
                    float d = tt - zzL[e];
                    g8[j] = f2bf(cmL[e] * __expf(d * d * nis2));
                }
                *(uint4*)&GT[(size_t)bx * 4096 + u * 8] = *(uint4*)g8;
            }
        }
    } else {
        int bid = bx - MAXCG;                       // 0..127
        const float* src = (bid & 64) ? Wa2 : Wp2;
        unsigned short* dst = (bid & 64) ? WfA : WfP;
        int rem = bid & 63;
        int kq = rem >> 2;                          // ks*4+q
        int s  = (rem & 3) * 256 + threadIdx.x;
        int ks = kq >> 2, q = kq & 3;
        unsigned short fr[8];
#pragma unroll
        for (int j = 0; j < 8; ++j)
            fr[j] = f2bf(src[(ks * 32 + q * 8 + j) * S_DIM + s]);
        ((u16x8*)dst)[kq * S_DIM + s] = *(u16x8*)fr;
    }
}

// ---------------- main fused kernel --------------------------------------
// grid: (NBKT*KSPL = 64, 16 s_tiles of 64), 256 threads (4 waves), 4 blk/CU.
__global__ __launch_bounds__(256, 4) void k_main(
    const unsigned short* __restrict__ HpS, const unsigned short* __restrict__ HaS,
    const unsigned short* __restrict__ WfP, const unsigned short* __restrict__ WfA,
    const float* __restrict__ bp2, const float* __restrict__ ba2,
    const int* __restrict__ meta, const unsigned short* __restrict__ GT,
    float* __restrict__ out) {

    const int bk     = blockIdx.x / KSPL;
    const int kspl   = blockIdx.x % KSPL;
    const int s0     = blockIdx.y * 64;
    const int tb     = bk * 64;                // t span [tb, tb+128)
    const int cnt    = meta[bk];
    const int pstart = meta[32 + bk];          // padded, multiple of 32
    const int nch    = (cnt + 31) >> 5;
    const int per    = (nch + KSPL - 1) / KSPL;
    const int c0     = kspl * per;
    const int c1     = min(nch, c0 + per);
    if (c0 >= c1) return;                      // uniform across block

    const int tid = threadIdx.x;
    const int w = tid >> 6, l = tid & 63, q = l >> 4, c = l & 15;

    // LDS: Hp/Ha stage (16 KB) + Rsp transpose (5 KB)
    __shared__ __align__(16) uint4 HpL[512];
    __shared__ __align__(16) uint4 HaL[512];
    __shared__ __align__(16) unsigned short RspL[64 * 40];

    // W2 fragments for this wave's 16 s-columns: 8 coalesced 16B loads.
    const u16x8* WfPv = (const u16x8*)WfP;
    const u16x8* WfAv = (const u16x8*)WfA;
    const int sg = s0 + w * 16 + c;
    u16x8 wP[4], wA[4];
#pragma unroll
    for (int ks = 0; ks < 4; ++ks) {
        wP[ks] = WfPv[(ks * 4 + q) * S_DIM + sg];
        wA[ks] = WfAv[(ks * 4 + q) * S_DIM + sg];
    }
    const float bp2v = bp2[sg];
    const float ba2v = ba2[sg];

    const f32x4 z4 = { 0.f, 0.f, 0.f, 0.f };
    f32x4 acc2[8];
#pragma unroll
    for (int n8 = 0; n8 < 8; ++n8) acc2[n8] = z4;

    const uint4* Hp4 = (const uint4*)HpS;
    const uint4* Ha4 = (const uint4*)HaS;
    const int cgBase = pstart >> 5;            // first chunk index of bucket
    const u16x8* StHp = (const u16x8*)HpL;
    const u16x8* StHa = (const u16x8*)HaL;

    // prefetch chunk c0 into registers
    size_t cb = (size_t)(cgBase + c0) * 512;
    uint4 p0 = Hp4[cb + tid], p1 = Hp4[cb + 256 + tid];
    uint4 a0 = Ha4[cb + tid], a1 = Ha4[cb + 256 + tid];

    for (int ci = c0; ci < c1; ++ci) {
        __syncthreads();                       // prior chunk's LDS reads done
        HpL[tid] = p0; HpL[256 + tid] = p1;
        HaL[tid] = a0; HaL[256 + tid] = a1;
        __syncthreads();

        // issue next chunk's prefetch (lands at next top barrier)
        int nc = min(ci + 1, c1 - 1);
        cb = (size_t)(cgBase + nc) * 512;
        p0 = Hp4[cb + tid]; p1 = Hp4[cb + 256 + tid];
        a0 = Ha4[cb + tid]; a1 = Ha4[cb + 256 + tid];

        // GT B-fragments direct from global (coalesced 1KB/wave, L1-shared)
        const unsigned short* gt = GT + (size_t)(cgBase + ci) * 4096;
        u16x8 bfr[8];
#pragma unroll
        for (int n8 = 0; n8 < 8; ++n8)
            bfr[n8] = *(const u16x8*)&gt[((n8 * 4 + q) * 16 + c) * 8];

        // GEMM1: C1[e][s] = H[e][k] @ W2[k][s]  (M=e 32, N=s 16/wave, K=128)
        f32x4 aP[2], aA[2];
#pragma unroll
        for (int m = 0; m < 2; ++m) { aP[m] = z4; aA[m] = z4; }
#pragma unroll
        for (int ks = 0; ks < 4; ++ks) {
            u16x8 hp0 = StHp[(ks * 4 + q) * 32 + c];
            u16x8 hp1 = StHp[(ks * 4 + q) * 32 + c + 16];
            u16x8 ha0 = StHa[(ks * 4 + q) * 32 + c];
            u16x8 ha1 = StHa[(ks * 4 + q) * 32 + c + 16];
            aP[0] = mfma16(hp0, wP[ks], aP[0]);
            aP[1] = mfma16(hp1, wP[ks], aP[1]);
            aA[0] = mfma16(ha0, wA[ks], aA[0]);
            aA[1] = mfma16(ha1, wA[ks], aA[1]);
        }

        // epilogue1: rsp = sigmoid(p+bp2)*(a+ba2); C-layout -> RspL[s][e]
        // rows wave-private; DS ops in-order per wave -> no barrier needed
#pragma unroll
        for (int m = 0; m < 2; ++m) {
            f32x4 p = aP[m], a = aA[m];
            unsigned long long pk = 0;
#pragma unroll
            for (int r = 0; r < 4; ++r) {
                float pr = p[r] + bp2v;
                float ar = a[r] + ba2v;
                float sg2 = __builtin_amdgcn_rcpf(1.f + __expf(-pr));
                pk |= (unsigned long long)f2bf(sg2 * ar) << (16 * r);
            }
            int sl = w * 16 + c;                 // col of C1 = s
            int e0 = m * 16 + q * 4;             // row of C1 = e
            *(unsigned long long*)&RspL[sl * 40 + e0] = pk;
        }

        // GEMM2: out[s][t] += Rsp[s][e] @ G[e][t]  (M=s 16/wave, N=t 128, K=32)
        u16x8 afr = *(const u16x8*)&RspL[(w * 16 + c) * 40 + q * 8];
#pragma unroll
        for (int n8 = 0; n8 < 8; ++n8)
            acc2[n8] = mfma16(afr, bfr[n8], acc2[n8]);
    }

    // epilogue2: atomic accumulate (bucket spans overlap + ksplit)
#pragma unroll
    for (int n8 = 0; n8 < 8; ++n8) {
        int t = tb + n8 * 16 + c;
        if (t < T_DIM) {
            int srow = s0 + w * 16 + q * 4;
#pragma unroll
            for (int r = 0; r < 4; ++r)
                atomicAdd(&out[(srow + r) * T_DIM + t], acc2[n8][r]);
        }
    }
}

// ---------------- launch ----------------

extern "C" void kernel_launch(void* const* d_in, const int* in_sizes, int n_in,
                              void* d_out, int out_size, void* d_ws, size_t ws_size,
                              hipStream_t stream) {
    const float* x    = (const float*)d_in[0];
    const float* zp   = (const float*)d_in[1];
    const float* mask = (const float*)d_in[2];
    const float* Wp1  = (const float*)d_in[3];
    const float* bp1  = (const float*)d_in[4];
    const float* Wp2  = (const float*)d_in[5];
    const float* bp2  = (const float*)d_in[6];
    const float* Wa1  = (const float*)d_in[7];
    const float* ba1  = (const float*)d_in[8];
    const float* Wa2  = (const float*)d_in[9];
    const float* ba2  = (const float*)d_in[10];
    const float* sig  = (const float*)d_in[11];

    char* ws = (char*)d_ws;
    unsigned short* HpS  = (unsigned short*)(ws);                      // 8,323,072 B
    unsigned short* HaS  = (unsigned short*)(ws + 8323072);            // 8,323,072 B
    unsigned short* WfP  = (unsigned short*)(ws + 16646144);           //   262,144 B
    unsigned short* WfA  = (unsigned short*)(ws + 16908288);           //   262,144 B
    int*            meta = (int*)(ws + 17170432);                      //       256 B
    int*            list = (int*)(ws + 17170688);                      //   130,048 B
    int*            bc   = (int*)(ws + 17300736);                      //     8,000 B
    unsigned short* GT   = (unsigned short*)(ws + 17308736);           // 8,323,072 B
    // total ws ~25.6 MB

    k_count<<<NBLK + 1024, 256, 0, stream>>>(zp, bc, (float*)d_out);
    k_fillscan<<<NBLK, 256, 0, stream>>>(zp, bc, meta, list);
    k_prep<<<MAXCG + 128, 256, 0, stream>>>(x, zp, mask, sig,
                                            Wp1, bp1, Wa1, ba1, Wp2, Wa2,
                                            meta, list, HpS, HaS, GT, WfP, WfA);
    k_main<<<dim3(NBKT * KSPL, 16, 1), 256, 0, stream>>>(
        HpS, HaS, WfP, WfA, bp2, ba2, meta, GT, (float*)d_out);
}